// Round 5
// baseline (1799.511 us; speedup 1.0000x reference)
//
#include <hip/hip_runtime.h>

// Problem: B*T=3200 seqs, V=25, D=128, N_Q=4, N_E=1024. NROWS=80000.
// d_out: zq [10,240,000] | loss [1] | indices [320,000]
#define ZQ_N    10240000
#define IDX_OFF 10240001
#define FLT_BIG 3.402823466e38f

typedef __bf16 bf16x8 __attribute__((ext_vector_type(8)));
typedef float  f32x4  __attribute__((ext_vector_type(4)));

__device__ __forceinline__ float getc(const float4& v, int k) {
    return k == 0 ? v.x : k == 1 ? v.y : k == 2 ? v.z : v.w;
}

// round-to-nearest-even fp32 -> bf16 (bit pattern), and back
__device__ __forceinline__ unsigned short f2bf(float f) {
    unsigned int u = __float_as_uint(f);
    unsigned int r = u + 0x7FFFu + ((u >> 16) & 1u);
    return (unsigned short)(r >> 16);
}
__device__ __forceinline__ float bf2f(unsigned short h) {
    return __uint_as_float(((unsigned int)h) << 16);
}

__global__ __launch_bounds__(256) void k_init(float* loss_part) {
    int i = blockIdx.x * 256 + threadIdx.x;
    if (i < 1024) loss_part[i] = 0.f;
}

// wsq[q*1024+j] = ||emb[q][j]||^2
__global__ __launch_bounds__(256) void k_wsq(const float* __restrict__ emb,
                                             float* __restrict__ wsq) {
    int t = threadIdx.x;
    int row = blockIdx.x * 64 + (t >> 2);
    int seg = t & 3;
    const float4* p = (const float4*)(emb + row * 128 + seg * 32);
    float a = 0.f;
#pragma unroll
    for (int i = 0; i < 8; i++) {
        float4 w = p[i];
        a = fmaf(w.x, w.x, a); a = fmaf(w.y, w.y, a);
        a = fmaf(w.z, w.z, a); a = fmaf(w.w, w.w, a);
    }
    a += __shfl_xor(a, 1);
    a += __shfl_xor(a, 2);
    if (seg == 0) wsq[row] = a;
}

// Pre-swizzle codebook into MFMA B-fragment order, bf16x3 split.
// swz flat index: ((((stage*64+cg)*4+kq)*3+comp)*64+lane)*8+j
//   col = cg*16 + (lane&15), k = kq*32 + (lane>>4)*8 + j
// One block per (stage,cg,kq): 1536 bf16 elems.
__global__ __launch_bounds__(256) void k_wswz(const float* __restrict__ emb,
                                              unsigned short* __restrict__ swz) {
    const int b = blockIdx.x;           // 4*64*4 = 1024 blocks
    const int stage = b >> 8;
    const int cg = (b >> 2) & 63;
    const int kq = b & 3;
    unsigned short* dst = swz + (size_t)b * 1536;
    for (int f = threadIdx.x; f < 1536; f += 256) {
        int comp = f >> 9;
        int r = f & 511;
        int lane = r >> 3, j = r & 7;
        int col = cg * 16 + (lane & 15);
        int k = kq * 32 + (lane >> 4) * 8 + j;
        float v = emb[((stage * 1024 + col) << 7) + k];
        unsigned short h = f2bf(v); float fh = bf2f(h);
        float r1 = v - fh;
        unsigned short m = f2bf(r1); float fm = bf2f(m);
        float r2 = r1 - fm;
        dst[f] = (comp == 0) ? h : (comp == 1) ? m : f2bf(r2);
    }
}

// dst[C][R] = src[R][C]^T, R,C multiples of 32.
__global__ __launch_bounds__(256) void k_transpose(const float* __restrict__ src,
                                                   float* __restrict__ dst,
                                                   int R, int C) {
    __shared__ float t[32][33];
    const int tx = threadIdx.x & 31, ty = threadIdx.x >> 5;
    const int r0 = blockIdx.y * 32, c0 = blockIdx.x * 32;
#pragma unroll
    for (int i = 0; i < 4; i++)
        t[ty + 8 * i][tx] = src[(size_t)(r0 + ty + 8 * i) * C + c0 + tx];
    __syncthreads();
#pragma unroll
    for (int i = 0; i < 4; i++)
        dst[(size_t)(c0 + ty + 8 * i) * R + r0 + tx] = t[tx][ty + 8 * i];
}

// One block per sequence: ring-GCN + linear(gwT) + LeakyReLU + LN + res add. (R2 verbatim)
__global__ __launch_bounds__(256) void k_refine(const float* __restrict__ src,
        float* __restrict__ refined, float* __restrict__ s_out,
        const float* __restrict__ An, const float* __restrict__ gwT,
        const float* __restrict__ gb, const float* __restrict__ lsc,
        const float* __restrict__ lbi) {
    __shared__ __align__(16) float Rn[25 * 128];
    __shared__ __align__(16) float nei[32 * 132];
    __shared__ float Al[625];
    const int tid = threadIdx.x;
    const int n = blockIdx.x;

    const float4* sp = (const float4*)(src + n * 3200);
    float4* Rn4 = (float4*)Rn;
    for (int i = tid; i < 800; i += 256) Rn4[i] = sp[i];
    for (int i = tid; i < 625; i += 256) Al[i] = An[i];
    __syncthreads();

    for (int i = tid; i < 3200; i += 256) {
        int v = i >> 7, d = i & 127;
        int vm = (v == 0) ? 24 : v - 1;
        int vp = (v == 24) ? 0 : v + 1;
        float val = Al[v * 25 + vm] * Rn[vm * 128 + d];
        val = fmaf(Al[v * 25 + v],  Rn[v  * 128 + d], val);
        val = fmaf(Al[v * 25 + vp], Rn[vp * 128 + d], val);
        nei[v * 132 + d] = val;
    }
    __syncthreads();

    const int dpg = tid & 31;
    const int vs  = tid >> 5;
    const int dp0 = dpg * 4;

    float acc[4][4];
#pragma unroll
    for (int a = 0; a < 4; a++)
#pragma unroll
        for (int b = 0; b < 4; b++) acc[a][b] = 0.f;

    for (int kg = 0; kg < 128; kg += 4) {
        float4 xv[4];
#pragma unroll
        for (int i = 0; i < 4; i++)
            xv[i] = *(const float4*)(&nei[(vs + 8 * i) * 132 + kg]);
#pragma unroll
        for (int kk = 0; kk < 4; kk++) {
            float4 w = *(const float4*)(gwT + (kg + kk) * 128 + dp0);
#pragma unroll
            for (int i = 0; i < 4; i++) {
                float xs = getc(xv[i], kk);
                acc[i][0] = fmaf(xs, w.x, acc[i][0]);
                acc[i][1] = fmaf(xs, w.y, acc[i][1]);
                acc[i][2] = fmaf(xs, w.z, acc[i][2]);
                acc[i][3] = fmaf(xs, w.w, acc[i][3]);
            }
        }
    }

    float4 b4  = *(const float4*)(gb + dp0);
    float4 sc4 = *(const float4*)(lsc + dp0);
    float4 bi4 = *(const float4*)(lbi + dp0);
    const float bb[4] = {b4.x, b4.y, b4.z, b4.w};
    const float sc[4] = {sc4.x, sc4.y, sc4.z, sc4.w};
    const float bi[4] = {bi4.x, bi4.y, bi4.z, bi4.w};

#pragma unroll
    for (int i = 0; i < 4; i++) {
        int v = vs + 8 * i;
        if (v >= 25) break;
        float y[4];
#pragma unroll
        for (int c = 0; c < 4; c++) {
            float t = acc[i][c] + bb[c];
            y[c] = (t >= 0.f) ? t : 0.2f * t;
        }
        float s1 = y[0] + y[1] + y[2] + y[3];
#pragma unroll
        for (int m = 1; m <= 16; m <<= 1) s1 += __shfl_xor(s1, m);
        float mu = s1 * (1.f / 128.f);
        float d2 = 0.f;
#pragma unroll
        for (int c = 0; c < 4; c++) { float t = y[c] - mu; d2 = fmaf(t, t, d2); }
#pragma unroll
        for (int m = 1; m <= 16; m <<= 1) d2 += __shfl_xor(d2, m);
        float inv = 1.f / sqrtf(d2 * (1.f / 128.f) + 1e-5f);

        float4 rn4 = *(const float4*)(&Rn[v * 128 + dp0]);
        const float rn[4] = {rn4.x, rn4.y, rn4.z, rn4.w};
        float o[4];
#pragma unroll
        for (int c = 0; c < 4; c++)
            o[c] = rn[c] + 0.1f * ((y[c] - mu) * inv * sc[c] + bi[c]);

        *(float4*)(refined + (n * 25 + v) * 128 + dp0) =
            make_float4(o[0], o[1], o[2], o[3]);

        float ss = 0.f;
#pragma unroll
        for (int c = 0; c < 4; c++) ss = fmaf(o[c], o[c], ss);
#pragma unroll
        for (int m = 1; m <= 16; m <<= 1) ss += __shfl_xor(ss, m);
        if (dpg == 0) s_out[n * 25 + v] = ss;
    }
}

// MFMA distance GEMM (bf16x3 split, swizzled B) + exact argmin + update. 64 rows, 4 waves.
__global__ __launch_bounds__(256, 3) void k_vq(const float* __restrict__ refined,
        const unsigned short* __restrict__ swz_k,  // this stage's swizzled codebook
        const float* __restrict__ emb_k, const float* __restrict__ wsq_k,
        const float* __restrict__ s_g,
        const float* res_src, float* res_dst, float* zq,
        float* __restrict__ idx_out, float* __restrict__ loss_part, int stage) {
    __shared__ __align__(16) unsigned short xh_s[64 * 136];  // row stride 136 (pad 8)
    __shared__ __align__(16) unsigned short xm_s[64 * 136];
    __shared__ __align__(16) unsigned short xl_s[64 * 136];
    __shared__ int il[64];
    const int tid = threadIdx.x;
    const int row0 = blockIdx.x * 64;

    // stage X tile: fp32 -> bf16x3 split into LDS
    for (int i = tid; i < 1024; i += 256) {       // 8-elem chunks
        int r = i >> 4, k8 = (i & 15) * 8;
        const float* srcp = refined + (row0 + r) * 128 + k8;
        float4 a = *(const float4*)(srcp);
        float4 b = *(const float4*)(srcp + 4);
        float vv[8] = {a.x, a.y, a.z, a.w, b.x, b.y, b.z, b.w};
        union { unsigned short us[8]; uint4 u4; } ph, pm, pl;
#pragma unroll
        for (int j = 0; j < 8; j++) {
            unsigned short h = f2bf(vv[j]); float fh = bf2f(h);
            float r1 = vv[j] - fh;
            unsigned short m = f2bf(r1); float fm = bf2f(m);
            float r2 = r1 - fm;
            ph.us[j] = h; pm.us[j] = m; pl.us[j] = f2bf(r2);
        }
        int off = r * 136 + k8;
        *(uint4*)(&xh_s[off]) = ph.u4;
        *(uint4*)(&xm_s[off]) = pm.u4;
        *(uint4*)(&xl_s[off]) = pl.u4;
    }
    __syncthreads();

    const int lane = tid & 63;
    const int w    = tid >> 6;       // wave id: cols w*64 within each 256-panel
    const int quad = lane >> 4;
    const int lm   = lane & 15;

    // ||x||^2 for the 16 rows this lane's C-frags cover
    float sr[16];
#pragma unroll
    for (int rt = 0; rt < 4; rt++) {
        float4 t = *(const float4*)(s_g + row0 + rt * 16 + quad * 4);
        sr[rt * 4 + 0] = t.x; sr[rt * 4 + 1] = t.y;
        sr[rt * 4 + 2] = t.z; sr[rt * 4 + 3] = t.w;
    }

    // cross-panel running best: lane (quad,lm) owns row (lm>>2)*16 + quad*4 + (lm&3)
    float rbv = FLT_BIG;
    int   rbi = 0x7FFFFFFF;

    for (int p = 0; p < 4; p++) {
        const int c0p = p * 256 + w * 64;
        const int cgbase = p * 16 + w * 4;    // 16-col group index base
        f32x4 acc[4][4];                      // [ct][rt]
#pragma unroll
        for (int a = 0; a < 4; a++)
#pragma unroll
            for (int b = 0; b < 4; b++) acc[a][b] = (f32x4){0.f, 0.f, 0.f, 0.f};

#pragma unroll
        for (int k0 = 0; k0 < 128; k0 += 32) {
            const int ko = k0 + quad * 8;
            const int kq = k0 >> 5;
            bf16x8 ah[4], am[4], al[4];
#pragma unroll
            for (int rt = 0; rt < 4; rt++) {
                int off = (rt * 16 + lm) * 136 + ko;
                ah[rt] = *(const bf16x8*)(&xh_s[off]);
                am[rt] = *(const bf16x8*)(&xm_s[off]);
                al[rt] = *(const bf16x8*)(&xl_s[off]);
            }
#pragma unroll
            for (int ct = 0; ct < 4; ct++) {
                // coalesced swizzled B: 16B/lane, h/m/l at +0/+512/+1024 elems
                const unsigned short* bp =
                    swz_k + (size_t)(((cgbase + ct) * 4 + kq) * 3) * 512 + lane * 8;
                bf16x8 bh = *(const bf16x8*)(bp);
                bf16x8 bm = *(const bf16x8*)(bp + 512);
                bf16x8 bl = *(const bf16x8*)(bp + 1024);
#pragma unroll
                for (int rt = 0; rt < 4; rt++)
                    acc[ct][rt] = __builtin_amdgcn_mfma_f32_16x16x32_bf16(ah[rt], bh, acc[ct][rt], 0, 0, 0);
#pragma unroll
                for (int rt = 0; rt < 4; rt++)
                    acc[ct][rt] = __builtin_amdgcn_mfma_f32_16x16x32_bf16(ah[rt], bm, acc[ct][rt], 0, 0, 0);
#pragma unroll
                for (int rt = 0; rt < 4; rt++)
                    acc[ct][rt] = __builtin_amdgcn_mfma_f32_16x16x32_bf16(am[rt], bh, acc[ct][rt], 0, 0, 0);
#pragma unroll
                for (int rt = 0; rt < 4; rt++)
                    acc[ct][rt] = __builtin_amdgcn_mfma_f32_16x16x32_bf16(ah[rt], bl, acc[ct][rt], 0, 0, 0);
#pragma unroll
                for (int rt = 0; rt < 4; rt++)
                    acc[ct][rt] = __builtin_amdgcn_mfma_f32_16x16x32_bf16(al[rt], bh, acc[ct][rt], 0, 0, 0);
#pragma unroll
                for (int rt = 0; rt < 4; rt++)
                    acc[ct][rt] = __builtin_amdgcn_mfma_f32_16x16x32_bf16(am[rt], bm, acc[ct][rt], 0, 0, 0);
            }
        }

        // panel epilogue: dist + in-lane argmin over this panel's 4 cols/lane
        float bestv[16];
        int   besti[16];
#pragma unroll
        for (int s = 0; s < 16; s++) { bestv[s] = FLT_BIG; besti[s] = 0x7FFFFFFF; }
#pragma unroll
        for (int ct = 0; ct < 4; ct++) {
            const int col = c0p + ct * 16 + lm;
            const float wq = wsq_k[col];
#pragma unroll
            for (int rt = 0; rt < 4; rt++) {
#pragma unroll
                for (int reg = 0; reg < 4; reg++) {
                    float d = (sr[rt * 4 + reg] - 2.0f * acc[ct][rt][reg]) + wq;
                    int s = rt * 4 + reg;
                    if (d < bestv[s] || (d == bestv[s] && col < besti[s])) {
                        bestv[s] = d; besti[s] = col;
                    }
                }
            }
        }
        // butterfly over lm; lane lm==s keeps row s's running best
#pragma unroll
        for (int s = 0; s < 16; s++) {
            float v = bestv[s]; int i2 = besti[s];
#pragma unroll
            for (int m = 1; m <= 8; m <<= 1) {
                float ov = __shfl_xor(v, m);
                int   oi = __shfl_xor(i2, m);
                if (ov < v || (ov == v && oi < i2)) { v = ov; i2 = oi; }
            }
            if (lm == s) {
                if (v < rbv || (v == rbv && i2 < rbi)) { rbv = v; rbi = i2; }
            }
        }
    }

    __syncthreads();                 // done reading x LDS; alias reduction buffers
    float* redv = (float*)xh_s;      // [4][64]
    int*   redi = (int*)xm_s;        // [4][64]
    {
        const int row = (lm >> 2) * 16 + quad * 4 + (lm & 3);
        redv[w * 64 + row] = rbv;
        redi[w * 64 + row] = rbi;
    }
    __syncthreads();
    if (tid < 64) {
        float bv = redv[tid]; int bi = redi[tid];
#pragma unroll
        for (int ww = 1; ww < 4; ww++) {
            float v2 = redv[ww * 64 + tid]; int i2 = redi[ww * 64 + tid];
            if (v2 < bv || (v2 == bv && i2 < bi)) { bv = v2; bi = i2; }
        }
        il[tid] = bi;
        idx_out[(row0 + tid) * 4 + stage] = (float)bi;
    }
    __syncthreads();

    // update: q = W[idx]; loss += ||q - res||^2; res -= q; cum += q   (R2 verbatim)
    const int r = tid >> 2, seg = tid & 3;
    const int row = row0 + r;
    const int idx = il[r];
    const float4* qp = (const float4*)(emb_k + idx * 128 + seg * 32);
    const float4* rp = (const float4*)(res_src + row * 128 + seg * 32);
    float4* rw = (float4*)(res_dst + row * 128 + seg * 32);
    float4* zp = (float4*)(zq + row * 128 + seg * 32);
    float accl = 0.f;
#pragma unroll
    for (int i = 0; i < 8; i++) {
        float4 q4 = qp[i];
        float4 r4 = rp[i];
        float dx = q4.x - r4.x, dy = q4.y - r4.y, dz = q4.z - r4.z, dw = q4.w - r4.w;
        accl = fmaf(dx, dx, accl); accl = fmaf(dy, dy, accl);
        accl = fmaf(dz, dz, accl); accl = fmaf(dw, dw, accl);
        rw[i] = make_float4(r4.x - q4.x, r4.y - q4.y, r4.z - q4.z, r4.w - q4.w);
        if (stage == 0) {
            zp[i] = q4;
        } else {
            float4 z4 = zp[i];
            zp[i] = make_float4(z4.x + q4.x, z4.y + q4.y, z4.z + q4.z, z4.w + q4.w);
        }
    }
    accl += __shfl_xor(accl, 1);  accl += __shfl_xor(accl, 2);
    accl += __shfl_xor(accl, 4);  accl += __shfl_xor(accl, 8);
    accl += __shfl_xor(accl, 16); accl += __shfl_xor(accl, 32);
    if ((tid & 63) == 0) atomicAdd(&loss_part[blockIdx.x & 1023], accl);
}

__global__ __launch_bounds__(256) void k_loss(const float* __restrict__ loss_part,
                                              float* __restrict__ out) {
    int t = threadIdx.x;
    float a = loss_part[t] + loss_part[t + 256] + loss_part[t + 512] + loss_part[t + 768];
#pragma unroll
    for (int m = 1; m <= 32; m <<= 1) a += __shfl_xor(a, m);
    __shared__ float w[4];
    if ((t & 63) == 0) w[t >> 6] = a;
    __syncthreads();
    if (t == 0) {
        float s = w[0] + w[1] + w[2] + w[3];
        out[ZQ_N] = s * (1.25f / (128.f * 320000.f));
    }
}

extern "C" void kernel_launch(void* const* d_in, const int* in_sizes, int n_in,
                              void* d_out, int out_size, void* d_ws, size_t ws_size,
                              hipStream_t stream) {
    (void)in_sizes; (void)n_in; (void)out_size; (void)ws_size;
    const float* z   = (const float*)d_in[0];
    const float* emb = (const float*)d_in[1];
    const float* An  = (const float*)d_in[2];
    const float* gw  = (const float*)d_in[3];
    const float* gb  = (const float*)d_in[4];
    const float* lsc = (const float*)d_in[5];
    const float* lbi = (const float*)d_in[6];

    float* out     = (float*)d_out;
    float* zq      = out;
    float* idx_out = out + IDX_OFF;

    float* ws        = (float*)d_ws;
    float* resbuf    = ws;                   // 10,240,000
    float* refined   = ws + 10240000;        // 10,240,000
    float* gwT       = ws + 20480000;        // 16,384
    unsigned short* swz = (unsigned short*)(ws + 20496384);  // 1,572,864 us = 786,432 f
    float* s_g       = ws + 21282816;        // 80,000
    float* wsq       = ws + 21362816;        // 4,096
    float* loss_part = ws + 21366912;        // 1,024  (end: 21,367,936 floats = 85.5 MB)

    k_init<<<4, 256, 0, stream>>>(loss_part);
    k_wsq<<<64, 256, 0, stream>>>(emb, wsq);
    k_wswz<<<1024, 256, 0, stream>>>(emb, swz);
    k_transpose<<<dim3(4, 4), 256, 0, stream>>>(gw, gwT, 128, 128);
    for (int k = 0; k < 4; k++) {
        const float* src = (k == 0) ? z : resbuf;
        k_refine<<<3200, 256, 0, stream>>>(src, refined, s_g, An, gwT, gb, lsc, lbi);
        k_vq<<<1250, 256, 0, stream>>>(refined,
                                       swz + (size_t)k * 393216,
                                       emb + k * 131072, wsq + k * 1024,
                                       s_g, src, resbuf, zq, idx_out, loss_part, k);
    }
    k_loss<<<1, 256, 0, stream>>>(loss_part, out);
}

// Round 6
// 1791.854 us; speedup vs baseline: 1.0043x; 1.0043x over previous
//
#include <hip/hip_runtime.h>

// Problem: B*T=3200 seqs, V=25, D=128, N_Q=4, N_E=1024. NROWS=80000.
// d_out: zq [10,240,000] | loss [1] | indices [320,000]
#define ZQ_N    10240000
#define IDX_OFF 10240001
#define FLT_BIG 3.402823466e38f

typedef __bf16 bf16x8 __attribute__((ext_vector_type(8)));
typedef float  f32x4  __attribute__((ext_vector_type(4)));

__device__ __forceinline__ float getc(const float4& v, int k) {
    return k == 0 ? v.x : k == 1 ? v.y : k == 2 ? v.z : v.w;
}

// round-to-nearest-even fp32 -> bf16 (bit pattern), and back
__device__ __forceinline__ unsigned short f2bf(float f) {
    unsigned int u = __float_as_uint(f);
    unsigned int r = u + 0x7FFFu + ((u >> 16) & 1u);
    return (unsigned short)(r >> 16);
}
__device__ __forceinline__ float bf2f(unsigned short h) {
    return __uint_as_float(((unsigned int)h) << 16);
}

__global__ __launch_bounds__(256) void k_init(float* loss_part) {
    int i = blockIdx.x * 256 + threadIdx.x;
    if (i < 1024) loss_part[i] = 0.f;
}

// wsq[q*1024+j] = ||emb[q][j]||^2
__global__ __launch_bounds__(256) void k_wsq(const float* __restrict__ emb,
                                             float* __restrict__ wsq) {
    int t = threadIdx.x;
    int row = blockIdx.x * 64 + (t >> 2);
    int seg = t & 3;
    const float4* p = (const float4*)(emb + row * 128 + seg * 32);
    float a = 0.f;
#pragma unroll
    for (int i = 0; i < 8; i++) {
        float4 w = p[i];
        a = fmaf(w.x, w.x, a); a = fmaf(w.y, w.y, a);
        a = fmaf(w.z, w.z, a); a = fmaf(w.w, w.w, a);
    }
    a += __shfl_xor(a, 1);
    a += __shfl_xor(a, 2);
    if (seg == 0) wsq[row] = a;
}

// Pre-swizzle codebook into MFMA B-fragment order, bf16x3 split.
// swz flat index: ((((stage*64+cg)*4+kq)*3+comp)*64+lane)*8+j
//   col = cg*16 + (lane&15), k = kq*32 + (lane>>4)*8 + j
__global__ __launch_bounds__(256) void k_wswz(const float* __restrict__ emb,
                                              unsigned short* __restrict__ swz) {
    const int b = blockIdx.x;           // 4*64*4 = 1024 blocks
    const int stage = b >> 8;
    const int cg = (b >> 2) & 63;
    const int kq = b & 3;
    unsigned short* dst = swz + (size_t)b * 1536;
    for (int f = threadIdx.x; f < 1536; f += 256) {
        int comp = f >> 9;
        int r = f & 511;
        int lane = r >> 3, j = r & 7;
        int col = cg * 16 + (lane & 15);
        int k = kq * 32 + (lane >> 4) * 8 + j;
        float v = emb[((stage * 1024 + col) << 7) + k];
        unsigned short h = f2bf(v); float fh = bf2f(h);
        float r1 = v - fh;
        unsigned short m = f2bf(r1); float fm = bf2f(m);
        float r2 = r1 - fm;
        dst[f] = (comp == 0) ? h : (comp == 1) ? m : f2bf(r2);
    }
}

// dst[C][R] = src[R][C]^T, R,C multiples of 32.
__global__ __launch_bounds__(256) void k_transpose(const float* __restrict__ src,
                                                   float* __restrict__ dst,
                                                   int R, int C) {
    __shared__ float t[32][33];
    const int tx = threadIdx.x & 31, ty = threadIdx.x >> 5;
    const int r0 = blockIdx.y * 32, c0 = blockIdx.x * 32;
#pragma unroll
    for (int i = 0; i < 4; i++)
        t[ty + 8 * i][tx] = src[(size_t)(r0 + ty + 8 * i) * C + c0 + tx];
    __syncthreads();
#pragma unroll
    for (int i = 0; i < 4; i++)
        dst[(size_t)(c0 + ty + 8 * i) * R + r0 + tx] = t[tx][ty + 8 * i];
}

// One block per sequence: ring-GCN + linear(gwT) + LeakyReLU + LN + res add. (R2 verbatim)
__global__ __launch_bounds__(256) void k_refine(const float* __restrict__ src,
        float* __restrict__ refined, float* __restrict__ s_out,
        const float* __restrict__ An, const float* __restrict__ gwT,
        const float* __restrict__ gb, const float* __restrict__ lsc,
        const float* __restrict__ lbi) {
    __shared__ __align__(16) float Rn[25 * 128];
    __shared__ __align__(16) float nei[32 * 132];
    __shared__ float Al[625];
    const int tid = threadIdx.x;
    const int n = blockIdx.x;

    const float4* sp = (const float4*)(src + n * 3200);
    float4* Rn4 = (float4*)Rn;
    for (int i = tid; i < 800; i += 256) Rn4[i] = sp[i];
    for (int i = tid; i < 625; i += 256) Al[i] = An[i];
    __syncthreads();

    for (int i = tid; i < 3200; i += 256) {
        int v = i >> 7, d = i & 127;
        int vm = (v == 0) ? 24 : v - 1;
        int vp = (v == 24) ? 0 : v + 1;
        float val = Al[v * 25 + vm] * Rn[vm * 128 + d];
        val = fmaf(Al[v * 25 + v],  Rn[v  * 128 + d], val);
        val = fmaf(Al[v * 25 + vp], Rn[vp * 128 + d], val);
        nei[v * 132 + d] = val;
    }
    __syncthreads();

    const int dpg = tid & 31;
    const int vs  = tid >> 5;
    const int dp0 = dpg * 4;

    float acc[4][4];
#pragma unroll
    for (int a = 0; a < 4; a++)
#pragma unroll
        for (int b = 0; b < 4; b++) acc[a][b] = 0.f;

    for (int kg = 0; kg < 128; kg += 4) {
        float4 xv[4];
#pragma unroll
        for (int i = 0; i < 4; i++)
            xv[i] = *(const float4*)(&nei[(vs + 8 * i) * 132 + kg]);
#pragma unroll
        for (int kk = 0; kk < 4; kk++) {
            float4 w = *(const float4*)(gwT + (kg + kk) * 128 + dp0);
#pragma unroll
            for (int i = 0; i < 4; i++) {
                float xs = getc(xv[i], kk);
                acc[i][0] = fmaf(xs, w.x, acc[i][0]);
                acc[i][1] = fmaf(xs, w.y, acc[i][1]);
                acc[i][2] = fmaf(xs, w.z, acc[i][2]);
                acc[i][3] = fmaf(xs, w.w, acc[i][3]);
            }
        }
    }

    float4 b4  = *(const float4*)(gb + dp0);
    float4 sc4 = *(const float4*)(lsc + dp0);
    float4 bi4 = *(const float4*)(lbi + dp0);
    const float bb[4] = {b4.x, b4.y, b4.z, b4.w};
    const float sc[4] = {sc4.x, sc4.y, sc4.z, sc4.w};
    const float bi[4] = {bi4.x, bi4.y, bi4.z, bi4.w};

#pragma unroll
    for (int i = 0; i < 4; i++) {
        int v = vs + 8 * i;
        if (v >= 25) break;
        float y[4];
#pragma unroll
        for (int c = 0; c < 4; c++) {
            float t = acc[i][c] + bb[c];
            y[c] = (t >= 0.f) ? t : 0.2f * t;
        }
        float s1 = y[0] + y[1] + y[2] + y[3];
#pragma unroll
        for (int m = 1; m <= 16; m <<= 1) s1 += __shfl_xor(s1, m);
        float mu = s1 * (1.f / 128.f);
        float d2 = 0.f;
#pragma unroll
        for (int c = 0; c < 4; c++) { float t = y[c] - mu; d2 = fmaf(t, t, d2); }
#pragma unroll
        for (int m = 1; m <= 16; m <<= 1) d2 += __shfl_xor(d2, m);
        float inv = 1.f / sqrtf(d2 * (1.f / 128.f) + 1e-5f);

        float4 rn4 = *(const float4*)(&Rn[v * 128 + dp0]);
        const float rn[4] = {rn4.x, rn4.y, rn4.z, rn4.w};
        float o[4];
#pragma unroll
        for (int c = 0; c < 4; c++)
            o[c] = rn[c] + 0.1f * ((y[c] - mu) * inv * sc[c] + bi[c]);

        *(float4*)(refined + (n * 25 + v) * 128 + dp0) =
            make_float4(o[0], o[1], o[2], o[3]);

        float ss = 0.f;
#pragma unroll
        for (int c = 0; c < 4; c++) ss = fmaf(o[c], o[c], ss);
#pragma unroll
        for (int m = 1; m <= 16; m <<= 1) ss += __shfl_xor(ss, m);
        if (dpg == 0) s_out[n * 25 + v] = ss;
    }
}

// MFMA distance GEMM (bf16x3 split, swizzled B) + exact argmin + update. 64 rows, 4 waves.
// NOTE: no min-waves bound — forcing 3 waves/SIMD (R5) spilled acc to scratch:
// FETCH 62->610 MB, dur 295->385 us. Let the allocator take ~200-240 VGPR.
__global__ __launch_bounds__(256) void k_vq(const float* __restrict__ refined,
        const unsigned short* __restrict__ swz_k,  // this stage's swizzled codebook
        const float* __restrict__ emb_k, const float* __restrict__ wsq_k,
        const float* __restrict__ s_g,
        const float* res_src, float* res_dst, float* zq,
        float* __restrict__ idx_out, float* __restrict__ loss_part, int stage) {
    __shared__ __align__(16) unsigned short xh_s[64 * 136];  // row stride 136 (pad 8)
    __shared__ __align__(16) unsigned short xm_s[64 * 136];
    __shared__ __align__(16) unsigned short xl_s[64 * 136];
    __shared__ int il[64];
    const int tid = threadIdx.x;
    const int row0 = blockIdx.x * 64;

    // stage X tile: fp32 -> bf16x3 split into LDS
    for (int i = tid; i < 1024; i += 256) {       // 8-elem chunks
        int r = i >> 4, k8 = (i & 15) * 8;
        const float* srcp = refined + (row0 + r) * 128 + k8;
        float4 a = *(const float4*)(srcp);
        float4 b = *(const float4*)(srcp + 4);
        float vv[8] = {a.x, a.y, a.z, a.w, b.x, b.y, b.z, b.w};
        union { unsigned short us[8]; uint4 u4; } ph, pm, pl;
#pragma unroll
        for (int j = 0; j < 8; j++) {
            unsigned short h = f2bf(vv[j]); float fh = bf2f(h);
            float r1 = vv[j] - fh;
            unsigned short m = f2bf(r1); float fm = bf2f(m);
            float r2 = r1 - fm;
            ph.us[j] = h; pm.us[j] = m; pl.us[j] = f2bf(r2);
        }
        int off = r * 136 + k8;
        *(uint4*)(&xh_s[off]) = ph.u4;
        *(uint4*)(&xm_s[off]) = pm.u4;
        *(uint4*)(&xl_s[off]) = pl.u4;
    }
    __syncthreads();

    const int lane = tid & 63;
    const int w    = tid >> 6;       // wave id: cols w*64 within each 256-panel
    const int quad = lane >> 4;
    const int lm   = lane & 15;

    // ||x||^2 for the 16 rows this lane's C-frags cover
    float sr[16];
#pragma unroll
    for (int rt = 0; rt < 4; rt++) {
        float4 t = *(const float4*)(s_g + row0 + rt * 16 + quad * 4);
        sr[rt * 4 + 0] = t.x; sr[rt * 4 + 1] = t.y;
        sr[rt * 4 + 2] = t.z; sr[rt * 4 + 3] = t.w;
    }

    // cross-panel running best: lane (quad,lm) owns row (lm>>2)*16 + quad*4 + (lm&3)
    float rbv = FLT_BIG;
    int   rbi = 0x7FFFFFFF;

    for (int p = 0; p < 4; p++) {
        const int c0p = p * 256 + w * 64;
        const int cgbase = p * 16 + w * 4;    // 16-col group index base
        f32x4 acc[4][4];                      // [ct][rt]
#pragma unroll
        for (int a = 0; a < 4; a++)
#pragma unroll
            for (int b = 0; b < 4; b++) acc[a][b] = (f32x4){0.f, 0.f, 0.f, 0.f};

#pragma unroll
        for (int k0 = 0; k0 < 128; k0 += 32) {
            const int ko = k0 + quad * 8;
            const int kq = k0 >> 5;
            bf16x8 ah[4], am[4], al[4];
#pragma unroll
            for (int rt = 0; rt < 4; rt++) {
                int off = (rt * 16 + lm) * 136 + ko;
                ah[rt] = *(const bf16x8*)(&xh_s[off]);
                am[rt] = *(const bf16x8*)(&xm_s[off]);
                al[rt] = *(const bf16x8*)(&xl_s[off]);
            }
#pragma unroll
            for (int ct = 0; ct < 4; ct++) {
                // coalesced swizzled B: 16B/lane, h/m/l at +0/+512/+1024 elems
                const unsigned short* bp =
                    swz_k + (size_t)(((cgbase + ct) * 4 + kq) * 3) * 512 + lane * 8;
                bf16x8 bh = *(const bf16x8*)(bp);
                bf16x8 bm = *(const bf16x8*)(bp + 512);
                bf16x8 bl = *(const bf16x8*)(bp + 1024);
#pragma unroll
                for (int rt = 0; rt < 4; rt++)
                    acc[ct][rt] = __builtin_amdgcn_mfma_f32_16x16x32_bf16(ah[rt], bh, acc[ct][rt], 0, 0, 0);
#pragma unroll
                for (int rt = 0; rt < 4; rt++)
                    acc[ct][rt] = __builtin_amdgcn_mfma_f32_16x16x32_bf16(ah[rt], bm, acc[ct][rt], 0, 0, 0);
#pragma unroll
                for (int rt = 0; rt < 4; rt++)
                    acc[ct][rt] = __builtin_amdgcn_mfma_f32_16x16x32_bf16(am[rt], bh, acc[ct][rt], 0, 0, 0);
#pragma unroll
                for (int rt = 0; rt < 4; rt++)
                    acc[ct][rt] = __builtin_amdgcn_mfma_f32_16x16x32_bf16(ah[rt], bl, acc[ct][rt], 0, 0, 0);
#pragma unroll
                for (int rt = 0; rt < 4; rt++)
                    acc[ct][rt] = __builtin_amdgcn_mfma_f32_16x16x32_bf16(al[rt], bh, acc[ct][rt], 0, 0, 0);
#pragma unroll
                for (int rt = 0; rt < 4; rt++)
                    acc[ct][rt] = __builtin_amdgcn_mfma_f32_16x16x32_bf16(am[rt], bm, acc[ct][rt], 0, 0, 0);
            }
        }

        // panel epilogue: dist + in-lane argmin over this panel's 4 cols/lane
        float bestv[16];
        int   besti[16];
#pragma unroll
        for (int s = 0; s < 16; s++) { bestv[s] = FLT_BIG; besti[s] = 0x7FFFFFFF; }
#pragma unroll
        for (int ct = 0; ct < 4; ct++) {
            const int col = c0p + ct * 16 + lm;
            const float wq = wsq_k[col];
#pragma unroll
            for (int rt = 0; rt < 4; rt++) {
#pragma unroll
                for (int reg = 0; reg < 4; reg++) {
                    float d = (sr[rt * 4 + reg] - 2.0f * acc[ct][rt][reg]) + wq;
                    int s = rt * 4 + reg;
                    if (d < bestv[s] || (d == bestv[s] && col < besti[s])) {
                        bestv[s] = d; besti[s] = col;
                    }
                }
            }
        }
        // butterfly over lm; lane lm==s keeps row s's running best
#pragma unroll
        for (int s = 0; s < 16; s++) {
            float v = bestv[s]; int i2 = besti[s];
#pragma unroll
            for (int m = 1; m <= 8; m <<= 1) {
                float ov = __shfl_xor(v, m);
                int   oi = __shfl_xor(i2, m);
                if (ov < v || (ov == v && oi < i2)) { v = ov; i2 = oi; }
            }
            if (lm == s) {
                if (v < rbv || (v == rbv && i2 < rbi)) { rbv = v; rbi = i2; }
            }
        }
    }

    __syncthreads();                 // done reading x LDS; alias reduction buffers
    float* redv = (float*)xh_s;      // [4][64]
    int*   redi = (int*)xm_s;        // [4][64]
    {
        const int row = (lm >> 2) * 16 + quad * 4 + (lm & 3);
        redv[w * 64 + row] = rbv;
        redi[w * 64 + row] = rbi;
    }
    __syncthreads();
    if (tid < 64) {
        float bv = redv[tid]; int bi = redi[tid];
#pragma unroll
        for (int ww = 1; ww < 4; ww++) {
            float v2 = redv[ww * 64 + tid]; int i2 = redi[ww * 64 + tid];
            if (v2 < bv || (v2 == bv && i2 < bi)) { bv = v2; bi = i2; }
        }
        il[tid] = bi;
        idx_out[(row0 + tid) * 4 + stage] = (float)bi;
    }
    __syncthreads();

    // update: q = W[idx]; loss += ||q - res||^2; res -= q; cum += q   (R2 verbatim)
    const int r = tid >> 2, seg = tid & 3;
    const int row = row0 + r;
    const int idx = il[r];
    const float4* qp = (const float4*)(emb_k + idx * 128 + seg * 32);
    const float4* rp = (const float4*)(res_src + row * 128 + seg * 32);
    float4* rw = (float4*)(res_dst + row * 128 + seg * 32);
    float4* zp = (float4*)(zq + row * 128 + seg * 32);
    float accl = 0.f;
#pragma unroll
    for (int i = 0; i < 8; i++) {
        float4 q4 = qp[i];
        float4 r4 = rp[i];
        float dx = q4.x - r4.x, dy = q4.y - r4.y, dz = q4.z - r4.z, dw = q4.w - r4.w;
        accl = fmaf(dx, dx, accl); accl = fmaf(dy, dy, accl);
        accl = fmaf(dz, dz, accl); accl = fmaf(dw, dw, accl);
        rw[i] = make_float4(r4.x - q4.x, r4.y - q4.y, r4.z - q4.z, r4.w - q4.w);
        if (stage == 0) {
            zp[i] = q4;
        } else {
            float4 z4 = zp[i];
            zp[i] = make_float4(z4.x + q4.x, z4.y + q4.y, z4.z + q4.z, z4.w + q4.w);
        }
    }
    accl += __shfl_xor(accl, 1);  accl += __shfl_xor(accl, 2);
    accl += __shfl_xor(accl, 4);  accl += __shfl_xor(accl, 8);
    accl += __shfl_xor(accl, 16); accl += __shfl_xor(accl, 32);
    if ((tid & 63) == 0) atomicAdd(&loss_part[blockIdx.x & 1023], accl);
}

__global__ __launch_bounds__(256) void k_loss(const float* __restrict__ loss_part,
                                              float* __restrict__ out) {
    int t = threadIdx.x;
    float a = loss_part[t] + loss_part[t + 256] + loss_part[t + 512] + loss_part[t + 768];
#pragma unroll
    for (int m = 1; m <= 32; m <<= 1) a += __shfl_xor(a, m);
    __shared__ float w[4];
    if ((t & 63) == 0) w[t >> 6] = a;
    __syncthreads();
    if (t == 0) {
        float s = w[0] + w[1] + w[2] + w[3];
        out[ZQ_N] = s * (1.25f / (128.f * 320000.f));
    }
}

extern "C" void kernel_launch(void* const* d_in, const int* in_sizes, int n_in,
                              void* d_out, int out_size, void* d_ws, size_t ws_size,
                              hipStream_t stream) {
    (void)in_sizes; (void)n_in; (void)out_size; (void)ws_size;
    const float* z   = (const float*)d_in[0];
    const float* emb = (const float*)d_in[1];
    const float* An  = (const float*)d_in[2];
    const float* gw  = (const float*)d_in[3];
    const float* gb  = (const float*)d_in[4];
    const float* lsc = (const float*)d_in[5];
    const float* lbi = (const float*)d_in[6];

    float* out     = (float*)d_out;
    float* zq      = out;
    float* idx_out = out + IDX_OFF;

    float* ws        = (float*)d_ws;
    float* resbuf    = ws;                   // 10,240,000
    float* refined   = ws + 10240000;        // 10,240,000
    float* gwT       = ws + 20480000;        // 16,384
    unsigned short* swz = (unsigned short*)(ws + 20496384);  // 1,572,864 us = 786,432 f
    float* s_g       = ws + 21282816;        // 80,000
    float* wsq       = ws + 21362816;        // 4,096
    float* loss_part = ws + 21366912;        // 1,024  (end: 21,367,936 floats = 85.5 MB)

    k_init<<<4, 256, 0, stream>>>(loss_part);
    k_wsq<<<64, 256, 0, stream>>>(emb, wsq);
    k_wswz<<<1024, 256, 0, stream>>>(emb, swz);
    k_transpose<<<dim3(4, 4), 256, 0, stream>>>(gw, gwT, 128, 128);
    for (int k = 0; k < 4; k++) {
        const float* src = (k == 0) ? z : resbuf;
        k_refine<<<3200, 256, 0, stream>>>(src, refined, s_g, An, gwT, gb, lsc, lbi);
        k_vq<<<1250, 256, 0, stream>>>(refined,
                                       swz + (size_t)k * 393216,
                                       emb + k * 131072, wsq + k * 1024,
                                       s_g, src, resbuf, zq, idx_out, loss_part, k);
    }
    k_loss<<<1, 256, 0, stream>>>(loss_part, out);
}

// Round 7
// 1438.966 us; speedup vs baseline: 1.2506x; 1.2452x over previous
//
#include <hip/hip_runtime.h>

// Problem: B*T=3200 seqs, V=25, D=128, N_Q=4, N_E=1024. NROWS=80000.
// d_out: zq [10,240,000] | loss [1] | indices [320,000]
#define ZQ_N    10240000
#define IDX_OFF 10240001
#define FLT_BIG 3.402823466e38f

typedef __bf16 bf16x8 __attribute__((ext_vector_type(8)));
typedef float  f32x4  __attribute__((ext_vector_type(4)));

__device__ __forceinline__ float getc(const float4& v, int k) {
    return k == 0 ? v.x : k == 1 ? v.y : k == 2 ? v.z : v.w;
}

// round-to-nearest-even fp32 -> bf16 (bit pattern), and back
__device__ __forceinline__ unsigned short f2bf(float f) {
    unsigned int u = __float_as_uint(f);
    unsigned int r = u + 0x7FFFu + ((u >> 16) & 1u);
    return (unsigned short)(r >> 16);
}
__device__ __forceinline__ float bf2f(unsigned short h) {
    return __uint_as_float(((unsigned int)h) << 16);
}

__global__ __launch_bounds__(256) void k_init(float* loss_part) {
    int i = blockIdx.x * 256 + threadIdx.x;
    if (i < 1024) loss_part[i] = 0.f;
}

// wsq[q*1024+j] = ||emb[q][j]||^2
__global__ __launch_bounds__(256) void k_wsq(const float* __restrict__ emb,
                                             float* __restrict__ wsq) {
    int t = threadIdx.x;
    int row = blockIdx.x * 64 + (t >> 2);
    int seg = t & 3;
    const float4* p = (const float4*)(emb + row * 128 + seg * 32);
    float a = 0.f;
#pragma unroll
    for (int i = 0; i < 8; i++) {
        float4 w = p[i];
        a = fmaf(w.x, w.x, a); a = fmaf(w.y, w.y, a);
        a = fmaf(w.z, w.z, a); a = fmaf(w.w, w.w, a);
    }
    a += __shfl_xor(a, 1);
    a += __shfl_xor(a, 2);
    if (seg == 0) wsq[row] = a;
}

// Pre-swizzle codebook into MFMA B-fragment order, bf16x3 split.
// swz flat index: ((((stage*64+cg)*4+kq)*3+comp)*64+lane)*8+j
//   col = cg*16 + (lane&15), k = kq*32 + (lane>>4)*8 + j
__global__ __launch_bounds__(256) void k_wswz(const float* __restrict__ emb,
                                              unsigned short* __restrict__ swz) {
    const int b = blockIdx.x;           // 4*64*4 = 1024 blocks
    const int stage = b >> 8;
    const int cg = (b >> 2) & 63;
    const int kq = b & 3;
    unsigned short* dst = swz + (size_t)b * 1536;
    for (int f = threadIdx.x; f < 1536; f += 256) {
        int comp = f >> 9;
        int r = f & 511;
        int lane = r >> 3, j = r & 7;
        int col = cg * 16 + (lane & 15);
        int k = kq * 32 + (lane >> 4) * 8 + j;
        float v = emb[((stage * 1024 + col) << 7) + k];
        unsigned short h = f2bf(v); float fh = bf2f(h);
        float r1 = v - fh;
        unsigned short m = f2bf(r1); float fm = bf2f(m);
        float r2 = r1 - fm;
        dst[f] = (comp == 0) ? h : (comp == 1) ? m : f2bf(r2);
    }
}

// dst[C][R] = src[R][C]^T, R,C multiples of 32.
__global__ __launch_bounds__(256) void k_transpose(const float* __restrict__ src,
                                                   float* __restrict__ dst,
                                                   int R, int C) {
    __shared__ float t[32][33];
    const int tx = threadIdx.x & 31, ty = threadIdx.x >> 5;
    const int r0 = blockIdx.y * 32, c0 = blockIdx.x * 32;
#pragma unroll
    for (int i = 0; i < 4; i++)
        t[ty + 8 * i][tx] = src[(size_t)(r0 + ty + 8 * i) * C + c0 + tx];
    __syncthreads();
#pragma unroll
    for (int i = 0; i < 4; i++)
        dst[(size_t)(c0 + ty + 8 * i) * R + r0 + tx] = t[tx][ty + 8 * i];
}

// One block per sequence: ring-GCN + linear(gwT) + LeakyReLU + LN + res add. (R2 verbatim)
__global__ __launch_bounds__(256) void k_refine(const float* __restrict__ src,
        float* __restrict__ refined, float* __restrict__ s_out,
        const float* __restrict__ An, const float* __restrict__ gwT,
        const float* __restrict__ gb, const float* __restrict__ lsc,
        const float* __restrict__ lbi) {
    __shared__ __align__(16) float Rn[25 * 128];
    __shared__ __align__(16) float nei[32 * 132];
    __shared__ float Al[625];
    const int tid = threadIdx.x;
    const int n = blockIdx.x;

    const float4* sp = (const float4*)(src + n * 3200);
    float4* Rn4 = (float4*)Rn;
    for (int i = tid; i < 800; i += 256) Rn4[i] = sp[i];
    for (int i = tid; i < 625; i += 256) Al[i] = An[i];
    __syncthreads();

    for (int i = tid; i < 3200; i += 256) {
        int v = i >> 7, d = i & 127;
        int vm = (v == 0) ? 24 : v - 1;
        int vp = (v == 24) ? 0 : v + 1;
        float val = Al[v * 25 + vm] * Rn[vm * 128 + d];
        val = fmaf(Al[v * 25 + v],  Rn[v  * 128 + d], val);
        val = fmaf(Al[v * 25 + vp], Rn[vp * 128 + d], val);
        nei[v * 132 + d] = val;
    }
    __syncthreads();

    const int dpg = tid & 31;
    const int vs  = tid >> 5;
    const int dp0 = dpg * 4;

    float acc[4][4];
#pragma unroll
    for (int a = 0; a < 4; a++)
#pragma unroll
        for (int b = 0; b < 4; b++) acc[a][b] = 0.f;

    for (int kg = 0; kg < 128; kg += 4) {
        float4 xv[4];
#pragma unroll
        for (int i = 0; i < 4; i++)
            xv[i] = *(const float4*)(&nei[(vs + 8 * i) * 132 + kg]);
#pragma unroll
        for (int kk = 0; kk < 4; kk++) {
            float4 w = *(const float4*)(gwT + (kg + kk) * 128 + dp0);
#pragma unroll
            for (int i = 0; i < 4; i++) {
                float xs = getc(xv[i], kk);
                acc[i][0] = fmaf(xs, w.x, acc[i][0]);
                acc[i][1] = fmaf(xs, w.y, acc[i][1]);
                acc[i][2] = fmaf(xs, w.z, acc[i][2]);
                acc[i][3] = fmaf(xs, w.w, acc[i][3]);
            }
        }
    }

    float4 b4  = *(const float4*)(gb + dp0);
    float4 sc4 = *(const float4*)(lsc + dp0);
    float4 bi4 = *(const float4*)(lbi + dp0);
    const float bb[4] = {b4.x, b4.y, b4.z, b4.w};
    const float sc[4] = {sc4.x, sc4.y, sc4.z, sc4.w};
    const float bi[4] = {bi4.x, bi4.y, bi4.z, bi4.w};

#pragma unroll
    for (int i = 0; i < 4; i++) {
        int v = vs + 8 * i;
        if (v >= 25) break;
        float y[4];
#pragma unroll
        for (int c = 0; c < 4; c++) {
            float t = acc[i][c] + bb[c];
            y[c] = (t >= 0.f) ? t : 0.2f * t;
        }
        float s1 = y[0] + y[1] + y[2] + y[3];
#pragma unroll
        for (int m = 1; m <= 16; m <<= 1) s1 += __shfl_xor(s1, m);
        float mu = s1 * (1.f / 128.f);
        float d2 = 0.f;
#pragma unroll
        for (int c = 0; c < 4; c++) { float t = y[c] - mu; d2 = fmaf(t, t, d2); }
#pragma unroll
        for (int m = 1; m <= 16; m <<= 1) d2 += __shfl_xor(d2, m);
        float inv = 1.f / sqrtf(d2 * (1.f / 128.f) + 1e-5f);

        float4 rn4 = *(const float4*)(&Rn[v * 128 + dp0]);
        const float rn[4] = {rn4.x, rn4.y, rn4.z, rn4.w};
        float o[4];
#pragma unroll
        for (int c = 0; c < 4; c++)
            o[c] = rn[c] + 0.1f * ((y[c] - mu) * inv * sc[c] + bi[c]);

        *(float4*)(refined + (n * 25 + v) * 128 + dp0) =
            make_float4(o[0], o[1], o[2], o[3]);

        float ss = 0.f;
#pragma unroll
        for (int c = 0; c < 4; c++) ss = fmaf(o[c], o[c], ss);
#pragma unroll
        for (int m = 1; m <= 16; m <<= 1) ss += __shfl_xor(ss, m);
        if (dpg == 0) s_out[n * 25 + v] = ss;
    }
}

// MFMA distance GEMM (bf16x3, swizzled B) + exact argmin + update. 64 rows, 4 waves.
// Tile: 64 rows x 32 cols per wave, 8 panels of 128 cols. Register-lean:
// acc 32 + best 32 + B 24 + A 12 streamed; ||x||^2 in LDS (not registers).
// Argmin: in-lane running best across panels (cols ascending), ONE butterfly at end
// (per-panel butterfly was the R6 regression: 382 vs 295 us).
// NO min-waves launch bound (R5: forcing 3 waves spilled acc -> FETCH 62->610 MB).
__global__ __launch_bounds__(256) void k_vq(const float* __restrict__ refined,
        const unsigned short* __restrict__ swz_k,  // this stage's swizzled codebook
        const float* __restrict__ emb_k, const float* __restrict__ wsq_k,
        const float* __restrict__ s_g,
        const float* res_src, float* res_dst, float* zq,
        float* __restrict__ idx_out, float* __restrict__ loss_part, int stage) {
    __shared__ __align__(16) unsigned short xh_s[64 * 136];  // row stride 136 (pad 8)
    __shared__ __align__(16) unsigned short xm_s[64 * 136];
    __shared__ __align__(16) unsigned short xl_s[64 * 136];
    __shared__ __align__(16) float s_lds[64];
    __shared__ int il[64];
    const int tid = threadIdx.x;
    const int row0 = blockIdx.x * 64;

    // stage X tile: fp32 -> bf16x3 split into LDS; ||x||^2 into LDS
    for (int i = tid; i < 1024; i += 256) {       // 8-elem chunks
        int r = i >> 4, k8 = (i & 15) * 8;
        const float* srcp = refined + (row0 + r) * 128 + k8;
        float4 a = *(const float4*)(srcp);
        float4 b = *(const float4*)(srcp + 4);
        float vv[8] = {a.x, a.y, a.z, a.w, b.x, b.y, b.z, b.w};
        union { unsigned short us[8]; uint4 u4; } ph, pm, pl;
#pragma unroll
        for (int j = 0; j < 8; j++) {
            unsigned short h = f2bf(vv[j]); float fh = bf2f(h);
            float r1 = vv[j] - fh;
            unsigned short m = f2bf(r1); float fm = bf2f(m);
            float r2 = r1 - fm;
            ph.us[j] = h; pm.us[j] = m; pl.us[j] = f2bf(r2);
        }
        int off = r * 136 + k8;
        *(uint4*)(&xh_s[off]) = ph.u4;
        *(uint4*)(&xm_s[off]) = pm.u4;
        *(uint4*)(&xl_s[off]) = pl.u4;
    }
    if (tid < 16) ((float4*)s_lds)[tid] = ((const float4*)(s_g + row0))[tid];
    __syncthreads();

    const int lane = tid & 63;
    const int w    = tid >> 6;       // wave id: cols w*32 within each 128-panel
    const int quad = lane >> 4;
    const int lm   = lane & 15;

    // running best per C-frag slot s=rt*4+reg (row = rt*16 + quad*4 + reg)
    float bestv[16];
    int   besti[16];
#pragma unroll
    for (int s = 0; s < 16; s++) { bestv[s] = FLT_BIG; besti[s] = 0x7FFFFFFF; }

    for (int p = 0; p < 8; p++) {
        const int cg0 = p * 8 + w * 2;          // 16-col group index of ct=0
        f32x4 acc[2][4];                         // [ct][rt]
#pragma unroll
        for (int a = 0; a < 2; a++)
#pragma unroll
            for (int b = 0; b < 4; b++) acc[a][b] = (f32x4){0.f, 0.f, 0.f, 0.f};

#pragma unroll
        for (int kq = 0; kq < 4; kq++) {
            const int ko = kq * 32 + quad * 8;
            // coalesced swizzled B: 16B/lane; ct/comp at fixed element offsets
            const unsigned short* bp =
                swz_k + (size_t)((cg0 * 4 + kq) * 3) * 512 + lane * 8;
            bf16x8 bh0 = *(const bf16x8*)(bp);
            bf16x8 bm0 = *(const bf16x8*)(bp + 512);
            bf16x8 bl0 = *(const bf16x8*)(bp + 1024);
            bf16x8 bh1 = *(const bf16x8*)(bp + 6144);        // ct=1: +4*3*512
            bf16x8 bm1 = *(const bf16x8*)(bp + 6144 + 512);
            bf16x8 bl1 = *(const bf16x8*)(bp + 6144 + 1024);
#pragma unroll
            for (int rt = 0; rt < 4; rt++) {
                const int off = (rt * 16 + lm) * 136 + ko;
                bf16x8 ah = *(const bf16x8*)(&xh_s[off]);
                bf16x8 am = *(const bf16x8*)(&xm_s[off]);
                bf16x8 al = *(const bf16x8*)(&xl_s[off]);
                // product order fixed (matches passing R4/R6): hh,hm,mh,hl,lh,mm
                acc[0][rt] = __builtin_amdgcn_mfma_f32_16x16x32_bf16(ah, bh0, acc[0][rt], 0, 0, 0);
                acc[0][rt] = __builtin_amdgcn_mfma_f32_16x16x32_bf16(ah, bm0, acc[0][rt], 0, 0, 0);
                acc[0][rt] = __builtin_amdgcn_mfma_f32_16x16x32_bf16(am, bh0, acc[0][rt], 0, 0, 0);
                acc[0][rt] = __builtin_amdgcn_mfma_f32_16x16x32_bf16(ah, bl0, acc[0][rt], 0, 0, 0);
                acc[0][rt] = __builtin_amdgcn_mfma_f32_16x16x32_bf16(al, bh0, acc[0][rt], 0, 0, 0);
                acc[0][rt] = __builtin_amdgcn_mfma_f32_16x16x32_bf16(am, bm0, acc[0][rt], 0, 0, 0);
                acc[1][rt] = __builtin_amdgcn_mfma_f32_16x16x32_bf16(ah, bh1, acc[1][rt], 0, 0, 0);
                acc[1][rt] = __builtin_amdgcn_mfma_f32_16x16x32_bf16(ah, bm1, acc[1][rt], 0, 0, 0);
                acc[1][rt] = __builtin_amdgcn_mfma_f32_16x16x32_bf16(am, bh1, acc[1][rt], 0, 0, 0);
                acc[1][rt] = __builtin_amdgcn_mfma_f32_16x16x32_bf16(ah, bl1, acc[1][rt], 0, 0, 0);
                acc[1][rt] = __builtin_amdgcn_mfma_f32_16x16x32_bf16(al, bh1, acc[1][rt], 0, 0, 0);
                acc[1][rt] = __builtin_amdgcn_mfma_f32_16x16x32_bf16(am, bm1, acc[1][rt], 0, 0, 0);
            }
        }

        // panel epilogue: dist = (||x||^2 - 2p) + ||w||^2, in-lane running argmin
#pragma unroll
        for (int ct = 0; ct < 2; ct++) {
            const int col = (cg0 + ct) * 16 + lm;
            const float wq = wsq_k[col];
#pragma unroll
            for (int rt = 0; rt < 4; rt++) {
                float4 sv4 = *(const float4*)(&s_lds[rt * 16 + quad * 4]);
#pragma unroll
                for (int reg = 0; reg < 4; reg++) {
                    float d = (getc(sv4, reg) - 2.0f * acc[ct][rt][reg]) + wq;
                    int s = rt * 4 + reg;
                    if (d < bestv[s] || (d == bestv[s] && col < besti[s])) {
                        bestv[s] = d; besti[s] = col;
                    }
                }
            }
        }
    }

    // ONE cross-lane butterfly over lm (16 lanes hold same rows, different cols)
#pragma unroll
    for (int s = 0; s < 16; s++) {
#pragma unroll
        for (int m = 1; m <= 8; m <<= 1) {
            float ov = __shfl_xor(bestv[s], m);
            int   oi = __shfl_xor(besti[s], m);
            if (ov < bestv[s] || (ov == bestv[s] && oi < besti[s])) {
                bestv[s] = ov; besti[s] = oi;
            }
        }
    }

    __syncthreads();                 // done reading x LDS; alias reduction buffers
    float* redv = (float*)xh_s;      // [4][64]
    int*   redi = (int*)xm_s;        // [4][64]
    if (lm == 0) {
#pragma unroll
        for (int s = 0; s < 16; s++) {
            int row = (s >> 2) * 16 + quad * 4 + (s & 3);
            redv[w * 64 + row] = bestv[s];
            redi[w * 64 + row] = besti[s];
        }
    }
    __syncthreads();
    if (tid < 64) {
        float bv = redv[tid]; int bi = redi[tid];
#pragma unroll
        for (int ww = 1; ww < 4; ww++) {
            float v2 = redv[ww * 64 + tid]; int i2 = redi[ww * 64 + tid];
            if (v2 < bv || (v2 == bv && i2 < bi)) { bv = v2; bi = i2; }
        }
        il[tid] = bi;
        idx_out[(row0 + tid) * 4 + stage] = (float)bi;
    }
    __syncthreads();

    // update: q = W[idx]; loss += ||q - res||^2; res -= q; cum += q   (R2 verbatim)
    const int r = tid >> 2, seg = tid & 3;
    const int row = row0 + r;
    const int idx = il[r];
    const float4* qp = (const float4*)(emb_k + idx * 128 + seg * 32);
    const float4* rp = (const float4*)(res_src + row * 128 + seg * 32);
    float4* rw = (float4*)(res_dst + row * 128 + seg * 32);
    float4* zp = (float4*)(zq + row * 128 + seg * 32);
    float accl = 0.f;
#pragma unroll
    for (int i = 0; i < 8; i++) {
        float4 q4 = qp[i];
        float4 r4 = rp[i];
        float dx = q4.x - r4.x, dy = q4.y - r4.y, dz = q4.z - r4.z, dw = q4.w - r4.w;
        accl = fmaf(dx, dx, accl); accl = fmaf(dy, dy, accl);
        accl = fmaf(dz, dz, accl); accl = fmaf(dw, dw, accl);
        rw[i] = make_float4(r4.x - q4.x, r4.y - q4.y, r4.z - q4.z, r4.w - q4.w);
        if (stage == 0) {
            zp[i] = q4;
        } else {
            float4 z4 = zp[i];
            zp[i] = make_float4(z4.x + q4.x, z4.y + q4.y, z4.z + q4.z, z4.w + q4.w);
        }
    }
    accl += __shfl_xor(accl, 1);  accl += __shfl_xor(accl, 2);
    accl += __shfl_xor(accl, 4);  accl += __shfl_xor(accl, 8);
    accl += __shfl_xor(accl, 16); accl += __shfl_xor(accl, 32);
    if ((tid & 63) == 0) atomicAdd(&loss_part[blockIdx.x & 1023], accl);
}

__global__ __launch_bounds__(256) void k_loss(const float* __restrict__ loss_part,
                                              float* __restrict__ out) {
    int t = threadIdx.x;
    float a = loss_part[t] + loss_part[t + 256] + loss_part[t + 512] + loss_part[t + 768];
#pragma unroll
    for (int m = 1; m <= 32; m <<= 1) a += __shfl_xor(a, m);
    __shared__ float w[4];
    if ((t & 63) == 0) w[t >> 6] = a;
    __syncthreads();
    if (t == 0) {
        float s = w[0] + w[1] + w[2] + w[3];
        out[ZQ_N] = s * (1.25f / (128.f * 320000.f));
    }
}

extern "C" void kernel_launch(void* const* d_in, const int* in_sizes, int n_in,
                              void* d_out, int out_size, void* d_ws, size_t ws_size,
                              hipStream_t stream) {
    (void)in_sizes; (void)n_in; (void)out_size; (void)ws_size;
    const float* z   = (const float*)d_in[0];
    const float* emb = (const float*)d_in[1];
    const float* An  = (const float*)d_in[2];
    const float* gw  = (const float*)d_in[3];
    const float* gb  = (const float*)d_in[4];
    const float* lsc = (const float*)d_in[5];
    const float* lbi = (const float*)d_in[6];

    float* out     = (float*)d_out;
    float* zq      = out;
    float* idx_out = out + IDX_OFF;

    float* ws        = (float*)d_ws;
    float* resbuf    = ws;                   // 10,240,000
    float* refined   = ws + 10240000;        // 10,240,000
    float* gwT       = ws + 20480000;        // 16,384
    unsigned short* swz = (unsigned short*)(ws + 20496384);  // 1,572,864 us = 786,432 f
    float* s_g       = ws + 21282816;        // 80,000
    float* wsq       = ws + 21362816;        // 4,096
    float* loss_part = ws + 21366912;        // 1,024  (end: 21,367,936 floats = 85.5 MB)

    k_init<<<4, 256, 0, stream>>>(loss_part);
    k_wsq<<<64, 256, 0, stream>>>(emb, wsq);
    k_wswz<<<1024, 256, 0, stream>>>(emb, swz);
    k_transpose<<<dim3(4, 4), 256, 0, stream>>>(gw, gwT, 128, 128);
    for (int k = 0; k < 4; k++) {
        const float* src = (k == 0) ? z : resbuf;
        k_refine<<<3200, 256, 0, stream>>>(src, refined, s_g, An, gwT, gb, lsc, lbi);
        k_vq<<<1250, 256, 0, stream>>>(refined,
                                       swz + (size_t)k * 393216,
                                       emb + k * 131072, wsq + k * 1024,
                                       s_g, src, resbuf, zq, idx_out, loss_part, k);
    }
    k_loss<<<1, 256, 0, stream>>>(loss_part, out);
}